// Round 8
// baseline (618.765 us; speedup 1.0000x reference)
//
#include <hip/hip_runtime.h>
#include <cstdint>
#include <cstddef>

typedef __attribute__((ext_vector_type(8))) short bf16x8;
typedef __attribute__((ext_vector_type(4))) float f32x4;

#define B_DIM 1024
#define L_SEQ 50
#define H_DIM 512
#define NITEM 50000
#define PSTRIDE 400

// fp32 -> bf16 round-to-nearest-even (finite inputs)
__device__ __forceinline__ unsigned short f2bf(float x) {
  unsigned u = __float_as_uint(x);
  return (unsigned short)((u + 0x7fffu + ((u >> 16) & 1u)) >> 16);
}
__device__ __forceinline__ unsigned pack2(float lo, float hi) {
  return (unsigned)f2bf(lo) | ((unsigned)f2bf(hi) << 16);
}
__device__ __forceinline__ void gld16(const unsigned short* g, unsigned short* l) {
  __builtin_amdgcn_global_load_lds((const __attribute__((address_space(1))) void*)g,
                                   (__attribute__((address_space(3))) void*)l, 16, 0, 0);
}
#define BAR() asm volatile("s_barrier" ::: "memory")

// ---------------- mean body (device) ----------------
__device__ __forceinline__ void mean_body(int b2, const int* __restrict__ item_ids,
                                          const int* __restrict__ item_len,
                                          const int* __restrict__ ent_ids,
                                          const int* __restrict__ ent_len,
                                          const int* __restrict__ word_ids,
                                          const int* __restrict__ word_len,
                                          const float* __restrict__ item_emb,
                                          const float* __restrict__ ent_emb,
                                          const float* __restrict__ word_emb,
                                          unsigned short* __restrict__ u_bf) {
  const int b = b2 >> 1;
  const int col = ((b2 & 1) << 8) + threadIdx.x;
  float out = 0.f;
  {
    const int len = item_len[b]; float a = 0.f;
#pragma unroll 4
    for (int l = 0; l < len; ++l) a += item_emb[(size_t)item_ids[b * L_SEQ + l] * H_DIM + col];
    out += a / (float)(len > 0 ? len : 1);
  }
  {
    const int len = ent_len[b]; float a = 0.f;
#pragma unroll 4
    for (int l = 0; l < len; ++l) a += ent_emb[(size_t)ent_ids[b * L_SEQ + l] * H_DIM + col];
    out += a / (float)(len > 0 ? len : 1);
  }
  {
    const int len = word_len[b]; float a = 0.f;
#pragma unroll 4
    for (int l = 0; l < len; ++l) a += word_emb[(size_t)word_ids[b * L_SEQ + l] * H_DIM + col];
    out += a / (float)(len > 0 ? len : 1);
  }
  u_bf[b * H_DIM + col] = f2bf(out / 3.f);
}

// standalone mean (fallback path)
__global__ void mean_kernel(const int* __restrict__ item_ids, const int* __restrict__ item_len,
                            const int* __restrict__ ent_ids, const int* __restrict__ ent_len,
                            const int* __restrict__ word_ids, const int* __restrict__ word_len,
                            const float* __restrict__ item_emb, const float* __restrict__ ent_emb,
                            const float* __restrict__ word_emb, unsigned short* __restrict__ u_bf) {
  mean_body(blockIdx.x, item_ids, item_len, ent_ids, ent_len, word_ids, word_len, item_emb,
            ent_emb, word_emb, u_bf);
}

// ---------------- transpose body: W[K][N] fp32 -> Wt[N][K] bf16, one 64x64 tile ----------------
__device__ __forceinline__ void transpose_body(const float* __restrict__ W,
                                               unsigned short* __restrict__ Wt, int K, int N,
                                               int k0, int n0, float (*tile)[65]) {
  const int tn = threadIdx.x & 63, tk = threadIdx.x >> 6;
  const int nv = (n0 + tn < N) ? n0 + tn : N - 1;
#pragma unroll
  for (int i = 0; i < 16; ++i)
    tile[tk + 4 * i][tn] = W[(size_t)(k0 + tk + 4 * i) * N + nv];
  __syncthreads();
  const int rn = threadIdx.x >> 2, ck = (threadIdx.x & 3) * 16;
  if (n0 + rn < N) {
    uint4 o[2];
    unsigned* po = (unsigned*)&o[0];
#pragma unroll
    for (int c = 0; c < 8; ++c)
      po[c] = pack2(tile[ck + 2 * c][rn], tile[ck + 2 * c + 1][rn]);
    *(uint4*)&Wt[(size_t)(n0 + rn) * K + k0 + ck] = o[0];
    *(uint4*)&Wt[(size_t)(n0 + rn) * K + k0 + ck + 8] = o[1];
  }
}

// ---------------- fused prep: mean || W2 transpose || W1 transpose (one launch) ----------------
// blocks [0,2048) = mean; [2048, 2048+25024) = W2t (32 k-tiles x 782 n-tiles); rest = W1t (8x32).
__global__ void prep_kernel(const int* __restrict__ item_ids, const int* __restrict__ item_len,
                            const int* __restrict__ ent_ids, const int* __restrict__ ent_len,
                            const int* __restrict__ word_ids, const int* __restrict__ word_len,
                            const float* __restrict__ item_emb, const float* __restrict__ ent_emb,
                            const float* __restrict__ word_emb, unsigned short* __restrict__ u_bf,
                            const float* __restrict__ W1, unsigned short* __restrict__ W1t,
                            const float* __restrict__ W2, unsigned short* __restrict__ W2t) {
  __shared__ float tile[64][65];
  const int b = blockIdx.x;
  if (b < 2048) {
    mean_body(b, item_ids, item_len, ent_ids, ent_len, word_ids, word_len, item_emb, ent_emb,
              word_emb, u_bf);
  } else if (b < 2048 + 25024) {
    const int t = b - 2048;
    transpose_body(W2, W2t, 2048, NITEM, (t & 31) * 64, (t >> 5) * 64, tile);
  } else {
    const int t = b - (2048 + 25024);
    transpose_body(W1, W1t, 512, 2048, (t & 7) * 64, (t >> 3) * 64, tile);
  }
}

// standalone transpose (fallback path never uses it; kept for completeness)
template <int K, int N>
__global__ void transpose_bf16(const float* __restrict__ W, unsigned short* __restrict__ Wt) {
  __shared__ float tile[64][65];
  transpose_body(W, Wt, K, N, blockIdx.x * 64, blockIdx.y * 64, tile);
}

// ---- K-half-ring 128x256 bf16 GEMM: C = A[M][K] * Bt[N][K]^T + bias (tail-optimized) ----
// 512 thr / 8 waves (2M x 4N), wave tile 64x64, acc 4x4. Half = 32 k of A[128] / B[256] rows.
// A-ring 4x8KB + B-ring 4x16KB = 96 KB -> 1 block/CU. Grid 8x196 = 1568 blocks -> 6.125
// rounds over 256 CUs (87.5% tail eff vs 76.6% at 784). Per half-step: {issue 3 gld16 (half
// h+3) | ds_read 8 frags | setprio+16 MFMA | counted vmcnt | barrier}. vmcnt(6) steady
// (halves h+2,h+3 in flight), 3 at HS-3, 0 at HS-2 — never 0 mid-loop. Slot h+3 == slot h-1,
// whose last read was before the previous barrier -> no overwrite race. Swizzle: LDS slot c
// holds global chunk c^((row>>1)&3) (2-way = free); inverse pre-applied to per-lane global
// address, gld16 dest linear (rule 21).
template <int K, int N, int EPI>
__global__ __launch_bounds__(512, 1) void gemm128x256(const unsigned short* __restrict__ Ag,
                                                      const unsigned short* __restrict__ Btg,
                                                      const float* __restrict__ bias,
                                                      unsigned short* __restrict__ Cbf,
                                                      float* __restrict__ Cf,
                                                      float* __restrict__ pmax,
                                                      float* __restrict__ psum) {
  __shared__ unsigned short lds[4 * 4096 + 4 * 8192];  // Aring | Bring (96 KB)
  unsigned short* Aring = lds;
  unsigned short* Bring = lds + 4 * 4096;

  const int tid = threadIdx.x;
  const int lane = tid & 63;
  const int wid = tid >> 6;

  // XCD grouping: nwg = 1568 = 8*196; contiguous wgid chunk per XCD
  const int nwg = gridDim.x;
  const int wgid = (blockIdx.x & 7) * (nwg >> 3) + (blockIdx.x >> 3);
  const int m0 = (wgid & 7) * 128;
  const int panel = wgid >> 3;
  const int n0 = panel * 256;

  // staging: thread -> (row = base + lane>>2, chunk = lane&3); pre-swizzled global chunk
  const int cg = (lane & 3) ^ ((lane >> 3) & 3);
  const int arow = wid * 16 + (lane >> 2);                 // A: 128 rows, 1 gld16/thread
  const unsigned short* pa = Ag + (size_t)(m0 + arow) * K + cg * 8;
  const int br0 = wid * 32 + (lane >> 2), br1 = br0 + 16;  // B: 256 rows, 2 gld16/thread
  int rg0 = n0 + br0; rg0 = rg0 < N ? rg0 : N - 1;         // ragged-N clamp (masked at epi)
  int rg1 = n0 + br1; rg1 = rg1 < N ? rg1 : N - 1;
  const unsigned short* pb0 = Btg + (size_t)rg0 * K + cg * 8;
  const unsigned short* pb1 = Btg + (size_t)rg1 * K + cg * 8;
  const int li0 = wid * 2, li1 = wid * 2 + 1;

  const int wr = wid >> 2, wc = wid & 3;
  const int l15 = lane & 15, kb = lane >> 4;
  f32x4 acc[4][4] = {};

  const int HS = K / 32;
  // prologue: stage halves 0,1,2 (A,B0,B1 per half = steady issue order)
#pragma unroll
  for (int hh = 0; hh < 3; ++hh) {
    const int ko = hh * 32;
    gld16(pa + ko, &Aring[hh * 4096 + wid * 512]);
    gld16(pb0 + ko, &Bring[hh * 8192 + li0 * 512]);
    gld16(pb1 + ko, &Bring[hh * 8192 + li1 * 512]);
  }
  asm volatile("s_waitcnt vmcnt(6)" ::: "memory");  // half 0 resident, 1&2 in flight
  BAR();

#pragma unroll 1
  for (int h = 0; h < HS; ++h) {
    const int slot = h & 3;
    const int nslot = (h + 3) & 3;
    const int kst = (h + 3) * 32;
    const unsigned short* As_ = &Aring[slot * 4096];
    const unsigned short* Bs_ = &Bring[slot * 8192];

    if (h + 3 < HS) {  // issue first: loads in flight under this step's LDS+MFMA work
      gld16(pa + kst, &Aring[nslot * 4096 + wid * 512]);
      gld16(pb0 + kst, &Bring[nslot * 8192 + li0 * 512]);
      gld16(pb1 + kst, &Bring[nslot * 8192 + li1 * 512]);
    }

    bf16x8 af[4], bf[4];
#pragma unroll
    for (int i = 0; i < 4; ++i) {
      const int row = wr * 64 + i * 16 + l15;
      af[i] = *(const bf16x8*)&As_[row * 32 + (kb ^ ((row >> 1) & 3)) * 8];
    }
#pragma unroll
    for (int j = 0; j < 4; ++j) {
      const int col = wc * 64 + j * 16 + l15;
      bf[j] = *(const bf16x8*)&Bs_[col * 32 + (kb ^ ((col >> 1) & 3)) * 8];
    }
    __builtin_amdgcn_s_setprio(1);
#pragma unroll
    for (int i = 0; i < 4; ++i)
#pragma unroll
      for (int j = 0; j < 4; ++j)
        acc[i][j] = __builtin_amdgcn_mfma_f32_16x16x32_bf16(af[i], bf[j], acc[i][j], 0, 0, 0);
    __builtin_amdgcn_s_setprio(0);

    if (h + 1 < HS) {
      if (h + 4 <= HS)
        asm volatile("s_waitcnt vmcnt(6)" ::: "memory");  // h+1 resident; h+2,h+3 in flight
      else if (h + 3 == HS)
        asm volatile("s_waitcnt vmcnt(3)" ::: "memory");
      else
        asm volatile("s_waitcnt vmcnt(0)" ::: "memory");
      BAR();
    }
  }

  // ---- epilogue: C/D layout col=lane&15, row=(lane>>4)*4+reg ----
  float bv[4];
  bool val[4];
#pragma unroll
  for (int j = 0; j < 4; ++j) {
    const int cgl = n0 + wc * 64 + 16 * j + l15;
    val[j] = (cgl < N);
    bv[j] = bias[val[j] ? cgl : 0];
  }
#pragma unroll
  for (int i = 0; i < 4; ++i) {
    const int rbase = m0 + wr * 64 + 16 * i + 4 * kb;
#pragma unroll
    for (int j = 0; j < 4; ++j) {
      if (val[j]) {
        const int cgl = n0 + wc * 64 + 16 * j + l15;
#pragma unroll
        for (int rr = 0; rr < 4; ++rr) {
          const float v = acc[i][j][rr] + bv[j];
          if (EPI == 0)
            Cbf[(size_t)(rbase + rr) * N + cgl] = f2bf(v > 0.f ? v : 0.f);
          else
            Cf[(size_t)(rbase + rr) * N + cgl] = v;
        }
      }
    }
  }

  if constexpr (EPI == 1) {
    // fused softmax pass-1 partials over this block's 256 cols (128 rows)
    __syncthreads();
    float* redm = (float*)&lds[0];
    float* reds = redm + 512;
#pragma unroll
    for (int i = 0; i < 4; ++i) {
#pragma unroll
      for (int rr = 0; rr < 4; ++rr) {
        float mx = -3.0e38f;
#pragma unroll
        for (int j = 0; j < 4; ++j)
          if (val[j]) mx = fmaxf(mx, acc[i][j][rr] + bv[j]);
#pragma unroll
        for (int d = 1; d < 16; d <<= 1) mx = fmaxf(mx, __shfl_xor(mx, d));
        float s = 0.f;
#pragma unroll
        for (int j = 0; j < 4; ++j)
          if (val[j]) s += expf(acc[i][j][rr] + bv[j] - mx);
#pragma unroll
        for (int d = 1; d < 16; d <<= 1) s += __shfl_xor(s, d);
        if (l15 == 0) {
          const int rw = wr * 64 + 16 * i + 4 * kb + rr;  // block-local row [0,128)
          redm[wc * 128 + rw] = mx;
          reds[wc * 128 + rw] = s;
        }
      }
    }
    __syncthreads();
    if (tid < 128) {
      float mm = redm[tid], ss = reds[tid];
#pragma unroll
      for (int w = 1; w < 4; ++w) {
        const float ma = redm[w * 128 + tid], sa = reds[w * 128 + tid];
        const float nm = fmaxf(mm, ma);
        ss = ss * expf(mm - nm) + sa * expf(ma - nm);
        mm = nm;
      }
      pmax[(size_t)(m0 + tid) * PSTRIDE + panel] = mm;
      psum[(size_t)(m0 + tid) * PSTRIDE + panel] = ss;
    }
  }
}

// ---------------- m97-structure 128x128 GEMM (GEMM1) ----------------
template <int K, int N, int EPI>
__global__ __launch_bounds__(256, 2) void gemm128(const unsigned short* __restrict__ Ag,
                                                  const unsigned short* __restrict__ Btg,
                                                  const float* __restrict__ bias,
                                                  unsigned short* __restrict__ Cbf,
                                                  float* __restrict__ Cf) {
  __shared__ unsigned short As[2][128 * 64];
  __shared__ unsigned short Bs[2][128 * 64];
  const int tid = threadIdx.x;
  const int lane = tid & 63;
  const int wid = tid >> 6;
  const int nwg = gridDim.x;
  const int wgid = (blockIdx.x & 7) * (nwg >> 3) + (blockIdx.x >> 3);
  const int m0 = (wgid & 7) * 128;
  const int n0 = (wgid >> 3) * 128;
  const int srsub = lane >> 3;
  const int scg = (lane & 7) ^ srsub;
  const unsigned short* pa[4];
  const unsigned short* pb[4];
#pragma unroll
  for (int qq = 0; qq < 4; ++qq) {
    const int seg = wid * 4 + qq;
    const int row = seg * 8 + srsub;
    pa[qq] = Ag + (size_t)(m0 + row) * K + scg * 8;
    int rg = n0 + row;
    rg = rg < N ? rg : N - 1;
    pb[qq] = Btg + (size_t)rg * K + scg * 8;
  }
  auto stage = [&](int t, int s) {
    const int ko = t * 64;
#pragma unroll
    for (int qq = 0; qq < 4; ++qq) {
      const int seg = wid * 4 + qq;
      gld16(pa[qq] + ko, &As[s][seg * 512]);
      gld16(pb[qq] + ko, &Bs[s][seg * 512]);
    }
  };
  const int wr = wid >> 1, wc = wid & 1;
  const int l15 = lane & 15, kb = lane >> 4;
  f32x4 acc[4][4] = {};
  auto compute = [&](int s) {
#pragma unroll
    for (int koi = 0; koi < 2; ++koi) {
      bf16x8 af[4], bf[4];
#pragma unroll
      for (int i = 0; i < 4; ++i) {
        const int row = wr * 64 + i * 16 + l15;
        af[i] = *(const bf16x8*)&As[s][row * 64 + ((koi * 4 + kb) ^ (row & 7)) * 8];
      }
#pragma unroll
      for (int j = 0; j < 4; ++j) {
        const int col = wc * 64 + j * 16 + l15;
        bf[j] = *(const bf16x8*)&Bs[s][col * 64 + ((koi * 4 + kb) ^ (col & 7)) * 8];
      }
#pragma unroll
      for (int i = 0; i < 4; ++i)
#pragma unroll
        for (int j = 0; j < 4; ++j)
          acc[i][j] = __builtin_amdgcn_mfma_f32_16x16x32_bf16(af[i], bf[j], acc[i][j], 0, 0, 0);
    }
  };
  const int NT = K / 64;
  stage(0, 0);
  asm volatile("s_waitcnt vmcnt(0)" ::: "memory");
  __syncthreads();
#pragma unroll 1
  for (int t = 0; t < NT; ++t) {
    if (t + 1 < NT) stage(t + 1, (t + 1) & 1);
    compute(t & 1);
    asm volatile("s_waitcnt vmcnt(0)" ::: "memory");
    __syncthreads();
  }
  float bv[4];
  bool val[4];
#pragma unroll
  for (int j = 0; j < 4; ++j) {
    const int cg2 = n0 + wc * 64 + 16 * j + l15;
    val[j] = (cg2 < N);
    bv[j] = bias[val[j] ? cg2 : 0];
  }
#pragma unroll
  for (int i = 0; i < 4; ++i) {
    const int rbase = m0 + wr * 64 + 16 * i + 4 * kb;
#pragma unroll
    for (int j = 0; j < 4; ++j) {
      if (val[j]) {
        const int cg2 = n0 + wc * 64 + 16 * j + l15;
#pragma unroll
        for (int rr = 0; rr < 4; ++rr) {
          const float v = acc[i][j][rr] + bv[j];
          if (EPI == 0)
            Cbf[(size_t)(rbase + rr) * N + cg2] = f2bf(v > 0.f ? v : 0.f);
          else
            Cf[(size_t)(rbase + rr) * N + cg2] = v;
        }
      }
    }
  }
}

// ======== fallback (round-2) GEMM, used when ws is too small for the bf16 W copies ========
template <int K, int N, int EPI>
__global__ __launch_bounds__(512, 2) void gemm_fused(const unsigned short* __restrict__ Ag,
                                                     const float* __restrict__ Bg,
                                                     const float* __restrict__ bias,
                                                     unsigned short* __restrict__ Cbf,
                                                     float* __restrict__ Cf,
                                                     float* __restrict__ pmax,
                                                     float* __restrict__ psum) {
  __shared__ unsigned short As[2][256 * 64];
  __shared__ uint4 Bs[2][8 * 128];
  const int tid = threadIdx.x;
  const int lane = tid & 63;
  const int wid = tid >> 6;
  const int m0 = blockIdx.x * 256;
  const int n0 = blockIdx.y * 128;
  const int arow = tid >> 3;
  const int ach = tid & 7;
  const int bn = 2 * lane;
  const int bk = 8 * wid;
  const int bcolg = (n0 + bn < N - 2) ? (n0 + bn) : (N - 2);
  uint4 areg[4];
  float2 breg[8];
  f32x4 acc[4][4] = {};
  auto stage_global = [&](int kt) {
    const int k0 = kt * 64;
#pragma unroll
    for (int qq = 0; qq < 4; ++qq)
      areg[qq] = *(const uint4*)&Ag[(size_t)(m0 + arow + 64 * qq) * K + k0 + 8 * ach];
#pragma unroll
    for (int i = 0; i < 8; ++i) breg[i] = *(const float2*)&Bg[(size_t)(k0 + bk + i) * N + bcolg];
  };
  auto stage_lds = [&](int buf) {
#pragma unroll
    for (int qq = 0; qq < 4; ++qq) {
      const int row = arow + 64 * qq;
      *(uint4*)&As[buf][row * 64 + ((8 * ach) ^ ((row & 7) * 8))] = areg[qq];
    }
    uint4 c0, c1;
    c0.x = pack2(breg[0].x, breg[1].x); c0.y = pack2(breg[2].x, breg[3].x);
    c0.z = pack2(breg[4].x, breg[5].x); c0.w = pack2(breg[6].x, breg[7].x);
    c1.x = pack2(breg[0].y, breg[1].y); c1.y = pack2(breg[2].y, breg[3].y);
    c1.z = pack2(breg[4].y, breg[5].y); c1.w = pack2(breg[6].y, breg[7].y);
    Bs[buf][wid * 128 + bn] = c0;
    Bs[buf][wid * 128 + bn + 1] = c1;
  };
  const int wr = wid & 3, wc = wid >> 2;
  const int mw = 64 * wr, nw = 64 * wc;
  const int l15 = lane & 15, kb = lane >> 4;
  auto compute = [&](int buf) {
#pragma unroll
    for (int koi = 0; koi < 2; ++koi) {
      bf16x8 af[4], bfv[4];
#pragma unroll
      for (int i = 0; i < 4; ++i) {
        const int row = mw + 16 * i + l15;
        af[i] = *(const bf16x8*)&As[buf][row * 64 + ((32 * koi + 8 * kb) ^ ((row & 7) * 8))];
      }
#pragma unroll
      for (int j = 0; j < 4; ++j)
        bfv[j] = *(const bf16x8*)&Bs[buf][(4 * koi + kb) * 128 + nw + 16 * j + l15];
#pragma unroll
      for (int i = 0; i < 4; ++i)
#pragma unroll
        for (int j = 0; j < 4; ++j)
          acc[i][j] = __builtin_amdgcn_mfma_f32_16x16x32_bf16(af[i], bfv[j], acc[i][j], 0, 0, 0);
    }
  };
  const int NT = K / 64;
  stage_global(0);
  stage_lds(0);
  __syncthreads();
  for (int t = 0; t < NT; ++t) {
    const int cur = t & 1;
    if (t + 1 < NT) stage_global(t + 1);
    compute(cur);
    if (t + 1 < NT) stage_lds(cur ^ 1);
    __syncthreads();
  }
  float bv[4];
  bool val[4];
#pragma unroll
  for (int j = 0; j < 4; ++j) {
    const int cg2 = n0 + nw + 16 * j + l15;
    val[j] = (cg2 < N);
    bv[j] = bias[val[j] ? cg2 : 0];
  }
#pragma unroll
  for (int i = 0; i < 4; ++i) {
    const int rbase = m0 + mw + 16 * i + 4 * kb;
#pragma unroll
    for (int j = 0; j < 4; ++j) {
      if (val[j]) {
        const int cg2 = n0 + nw + 16 * j + l15;
#pragma unroll
        for (int rr = 0; rr < 4; ++rr) {
          const float v = acc[i][j][rr] + bv[j];
          if (EPI == 0)
            Cbf[(size_t)(rbase + rr) * N + cg2] = f2bf(v > 0.f ? v : 0.f);
          else
            Cf[(size_t)(rbase + rr) * N + cg2] = v;
        }
      }
    }
  }
  if constexpr (EPI == 1) {
    float* redm = (float*)&As[0][0];
    float* reds = redm + 512;
#pragma unroll
    for (int i = 0; i < 4; ++i) {
#pragma unroll
      for (int rr = 0; rr < 4; ++rr) {
        float mx = -3.0e38f;
#pragma unroll
        for (int j = 0; j < 4; ++j)
          if (val[j]) mx = fmaxf(mx, acc[i][j][rr] + bv[j]);
#pragma unroll
        for (int d = 1; d < 16; d <<= 1) mx = fmaxf(mx, __shfl_xor(mx, d));
        float s = 0.f;
#pragma unroll
        for (int j = 0; j < 4; ++j)
          if (val[j]) s += expf(acc[i][j][rr] + bv[j] - mx);
#pragma unroll
        for (int d = 1; d < 16; d <<= 1) s += __shfl_xor(s, d);
        if (l15 == 0) {
          const int rl = mw + 16 * i + 4 * kb + rr;
          redm[wc * 256 + rl] = mx;
          reds[wc * 256 + rl] = s;
        }
      }
    }
    __syncthreads();
    if (tid < 256) {
      const float ma = redm[tid], mb = redm[256 + tid];
      const float mm = fmaxf(ma, mb);
      const float ss = reds[tid] * expf(ma - mm) + reds[256 + tid] * expf(mb - mm);
      pmax[(size_t)(m0 + tid) * PSTRIDE + blockIdx.y] = mm;
      psum[(size_t)(m0 + tid) * PSTRIDE + blockIdx.y] = ss;
    }
  }
}

// ---------------- reduce per-block partials -> row max & sumexp ----------------
__global__ void smax1r(const float* __restrict__ pmax, const float* __restrict__ psum,
                       float* __restrict__ rms, int ntiles) {
  const int b = blockIdx.x;
  const int l = threadIdx.x;
  float m = -3.4e38f, s = 0.f;
  for (int i = l; i < ntiles; i += 64) {
    const float pm = pmax[(size_t)b * PSTRIDE + i];
    const float ps = psum[(size_t)b * PSTRIDE + i];
    const float nm = fmaxf(m, pm);
    s = s * expf(m - nm) + ps * expf(pm - nm);
    m = nm;
  }
  for (int d = 1; d < 64; d <<= 1) {
    const float om = __shfl_xor(m, d), os = __shfl_xor(s, d);
    const float nm = fmaxf(m, om);
    s = s * expf(m - nm) + os * expf(om - nm);
    m = nm;
  }
  if (l == 0) {
    rms[b] = m;
    rms[B_DIM + b] = s;
  }
}

// ---------------- softmax pass 2: probs in-place + log_softmax(probs) at label ----------------
__global__ void smax2(float* __restrict__ buf, const float* __restrict__ rms,
                      const int* __restrict__ labels, float* __restrict__ row_lp) {
  const int b = blockIdx.x;
  float4* p = (float4*)(buf + (size_t)b * NITEM);
  const float m = rms[b];
  const float inv = 1.f / rms[B_DIM + b];  // = max(probs)
  const int lab = labels[b];
  __shared__ float s_pl;
  __shared__ float ss[256];
  float s2 = 0.f;
  for (int i = threadIdx.x; i < NITEM / 4; i += 256) {
    const float4 v = p[i];
    float pr[4];
#pragma unroll
    for (int j = 0; j < 4; ++j) {
      pr[j] = expf((&v.x)[j] - m) * inv;
      s2 += expf(pr[j] - inv);
    }
    float4 w;
    w.x = pr[0]; w.y = pr[1]; w.z = pr[2]; w.w = pr[3];
    p[i] = w;
    if ((lab >> 2) == i) s_pl = pr[lab & 3];
  }
  ss[threadIdx.x] = s2;
  __syncthreads();
  for (int off = 128; off > 0; off >>= 1) {
    if (threadIdx.x < off) ss[threadIdx.x] += ss[threadIdx.x + off];
    __syncthreads();
  }
  if (threadIdx.x == 0) row_lp[b] = s_pl - (inv + logf(ss[0]));
}

// ---------------- finalize: labels (as float) + loss ----------------
__global__ void fin(const float* __restrict__ row_lp, const int* __restrict__ labels,
                    float* __restrict__ out) {
  __shared__ float sb[256];
  float a = 0.f;
  for (int i = threadIdx.x; i < B_DIM; i += 256) {
    a += row_lp[i];
    out[(size_t)B_DIM * NITEM + i] = (float)labels[i];
  }
  sb[threadIdx.x] = a;
  __syncthreads();
  for (int off = 128; off > 0; off >>= 1) {
    if (threadIdx.x < off) sb[threadIdx.x] += sb[threadIdx.x + off];
    __syncthreads();
  }
  if (threadIdx.x == 0) out[(size_t)B_DIM * NITEM + B_DIM] = -sb[0] / (float)B_DIM;
}

extern "C" void kernel_launch(void* const* d_in, const int* in_sizes, int n_in,
                              void* d_out, int out_size, void* d_ws, size_t ws_size,
                              hipStream_t stream) {
  const int* item_ids = (const int*)d_in[0];
  const int* item_len = (const int*)d_in[1];
  const int* ent_ids = (const int*)d_in[2];
  const int* ent_len = (const int*)d_in[3];
  const int* word_ids = (const int*)d_in[4];
  const int* word_len = (const int*)d_in[5];
  const int* labels = (const int*)d_in[6];
  const float* item_emb = (const float*)d_in[7];
  const float* ent_emb = (const float*)d_in[8];
  const float* word_emb = (const float*)d_in[9];
  const float* W1 = (const float*)d_in[10];
  const float* b1 = (const float*)d_in[11];
  const float* W2 = (const float*)d_in[12];
  const float* b2 = (const float*)d_in[13];

  float* out = (float*)d_out;
  char* ws = (char*)d_ws;
  unsigned short* u_bf = (unsigned short*)ws;                 // 1 MB   [1024][512] bf16
  unsigned short* h_bf = (unsigned short*)(ws + (1 << 20));   // 4 MB   [1024][2048] bf16
  float* pmax = (float*)(ws + 5 * (1 << 20));                 // 1.6 MB [1024][400]
  float* psum = (float*)(ws + 7 * (1 << 20));                 // 1.6 MB
  float* rms = (float*)(ws + 9 * (1 << 20));                  // [2][1024]
  float* row_lp = rms + 2 * B_DIM;
  unsigned short* W1t = (unsigned short*)(ws + 10 * (1 << 20));  // 2 MB [2048][512] bf16
  unsigned short* W2t = (unsigned short*)(ws + 16 * (1 << 20));  // 204.8 MB [50000][2048] bf16
  float* logits = out;

  const size_t need = (size_t)16 * (1 << 20) + (size_t)NITEM * 2048 * 2;
  const bool fast = ws_size >= need;

  if (fast) {
    prep_kernel<<<2048 + 25024 + 256, 256, 0, stream>>>(item_ids, item_len, ent_ids, ent_len,
                                                        word_ids, word_len, item_emb, ent_emb,
                                                        word_emb, u_bf, W1, W1t, W2, W2t);
    gemm128<512, 2048, 0><<<8 * 16, 256, 0, stream>>>(u_bf, W1t, b1, h_bf, nullptr);
    gemm128x256<2048, NITEM, 1><<<8 * 196, 512, 0, stream>>>(h_bf, W2t, b2, nullptr, logits,
                                                             pmax, psum);
    smax1r<<<B_DIM, 64, 0, stream>>>(pmax, psum, rms, 196);
  } else {
    mean_kernel<<<2 * B_DIM, 256, 0, stream>>>(item_ids, item_len, ent_ids, ent_len, word_ids,
                                               word_len, item_emb, ent_emb, word_emb, u_bf);
    gemm_fused<512, 2048, 0><<<dim3(4, 16), 512, 0, stream>>>(u_bf, W1, b1, h_bf, nullptr,
                                                              nullptr, nullptr);
    gemm_fused<2048, NITEM, 1><<<dim3(4, 391), 512, 0, stream>>>(h_bf, W2, b2, nullptr, logits,
                                                                 pmax, psum);
    smax1r<<<B_DIM, 64, 0, stream>>>(pmax, psum, rms, 391);
  }
  smax2<<<B_DIM, 256, 0, stream>>>(logits, rms, labels, row_lp);
  fin<<<1, 256, 0, stream>>>(row_lp, labels, out);
}

// Round 9
// 561.706 us; speedup vs baseline: 1.1016x; 1.1016x over previous
//
#include <hip/hip_runtime.h>
#include <cstdint>
#include <cstddef>

typedef __attribute__((ext_vector_type(8))) short bf16x8;
typedef __attribute__((ext_vector_type(4))) float f32x4;

#define B_DIM 1024
#define L_SEQ 50
#define H_DIM 512
#define NITEM 50000
#define PSTRIDE 400

// fp32 -> bf16 round-to-nearest-even (finite inputs)
__device__ __forceinline__ unsigned short f2bf(float x) {
  unsigned u = __float_as_uint(x);
  return (unsigned short)((u + 0x7fffu + ((u >> 16) & 1u)) >> 16);
}
__device__ __forceinline__ unsigned pack2(float lo, float hi) {
  return (unsigned)f2bf(lo) | ((unsigned)f2bf(hi) << 16);
}
__device__ __forceinline__ void gld16(const unsigned short* g, unsigned short* l) {
  __builtin_amdgcn_global_load_lds((const __attribute__((address_space(1))) void*)g,
                                   (__attribute__((address_space(3))) void*)l, 16, 0, 0);
}
#define BAR() asm volatile("s_barrier" ::: "memory")

// ---------------- mean body (device) ----------------
__device__ __forceinline__ void mean_body(int b2, const int* __restrict__ item_ids,
                                          const int* __restrict__ item_len,
                                          const int* __restrict__ ent_ids,
                                          const int* __restrict__ ent_len,
                                          const int* __restrict__ word_ids,
                                          const int* __restrict__ word_len,
                                          const float* __restrict__ item_emb,
                                          const float* __restrict__ ent_emb,
                                          const float* __restrict__ word_emb,
                                          unsigned short* __restrict__ u_bf) {
  const int b = b2 >> 1;
  const int col = ((b2 & 1) << 8) + threadIdx.x;
  float out = 0.f;
  {
    const int len = item_len[b]; float a = 0.f;
#pragma unroll 4
    for (int l = 0; l < len; ++l) a += item_emb[(size_t)item_ids[b * L_SEQ + l] * H_DIM + col];
    out += a / (float)(len > 0 ? len : 1);
  }
  {
    const int len = ent_len[b]; float a = 0.f;
#pragma unroll 4
    for (int l = 0; l < len; ++l) a += ent_emb[(size_t)ent_ids[b * L_SEQ + l] * H_DIM + col];
    out += a / (float)(len > 0 ? len : 1);
  }
  {
    const int len = word_len[b]; float a = 0.f;
#pragma unroll 4
    for (int l = 0; l < len; ++l) a += word_emb[(size_t)word_ids[b * L_SEQ + l] * H_DIM + col];
    out += a / (float)(len > 0 ? len : 1);
  }
  u_bf[b * H_DIM + col] = f2bf(out / 3.f);
}

__global__ void mean_kernel(const int* __restrict__ item_ids, const int* __restrict__ item_len,
                            const int* __restrict__ ent_ids, const int* __restrict__ ent_len,
                            const int* __restrict__ word_ids, const int* __restrict__ word_len,
                            const float* __restrict__ item_emb, const float* __restrict__ ent_emb,
                            const float* __restrict__ word_emb, unsigned short* __restrict__ u_bf) {
  mean_body(blockIdx.x, item_ids, item_len, ent_ids, ent_len, word_ids, word_len, item_emb,
            ent_emb, word_emb, u_bf);
}

// ---------------- transpose body: W[K][N] fp32 -> Wt[N][K] bf16, one 64x64 tile ----------------
__device__ __forceinline__ void transpose_body(const float* __restrict__ W,
                                               unsigned short* __restrict__ Wt, int K, int N,
                                               int k0, int n0, float (*tile)[65]) {
  const int tn = threadIdx.x & 63, tk = threadIdx.x >> 6;
  const int nv = (n0 + tn < N) ? n0 + tn : N - 1;
#pragma unroll
  for (int i = 0; i < 16; ++i)
    tile[tk + 4 * i][tn] = W[(size_t)(k0 + tk + 4 * i) * N + nv];
  __syncthreads();
  const int rn = threadIdx.x >> 2, ck = (threadIdx.x & 3) * 16;
  if (n0 + rn < N) {
    uint4 o[2];
    unsigned* po = (unsigned*)&o[0];
#pragma unroll
    for (int c = 0; c < 8; ++c)
      po[c] = pack2(tile[ck + 2 * c][rn], tile[ck + 2 * c + 1][rn]);
    *(uint4*)&Wt[(size_t)(n0 + rn) * K + k0 + ck] = o[0];
    *(uint4*)&Wt[(size_t)(n0 + rn) * K + k0 + ck + 8] = o[1];
  }
}

// ---------------- fused prep: mean || W2 transpose || W1 transpose (one launch) ----------------
__global__ void prep_kernel(const int* __restrict__ item_ids, const int* __restrict__ item_len,
                            const int* __restrict__ ent_ids, const int* __restrict__ ent_len,
                            const int* __restrict__ word_ids, const int* __restrict__ word_len,
                            const float* __restrict__ item_emb, const float* __restrict__ ent_emb,
                            const float* __restrict__ word_emb, unsigned short* __restrict__ u_bf,
                            const float* __restrict__ W1, unsigned short* __restrict__ W1t,
                            const float* __restrict__ W2, unsigned short* __restrict__ W2t) {
  __shared__ float tile[64][65];
  const int b = blockIdx.x;
  if (b < 2048) {
    mean_body(b, item_ids, item_len, ent_ids, ent_len, word_ids, word_len, item_emb, ent_emb,
              word_emb, u_bf);
  } else if (b < 2048 + 25024) {
    const int t = b - 2048;
    transpose_body(W2, W2t, 2048, NITEM, (t & 31) * 64, (t >> 5) * 64, tile);
  } else {
    const int t = b - (2048 + 25024);
    transpose_body(W1, W1t, 512, 2048, (t & 7) * 64, (t >> 3) * 64, tile);
  }
}

// ------------- K-half-ring 256x256 bf16 GEMM (R7-proven): C = A*Bt^T + bias -------------
// 512 thr / 8 waves (2M x 4N), wave tile 128x64, acc 8x4. Half = [256 rows][32 k] (16 KB).
// A-ring[4] + B-ring[4] = 128 KB. Per half-step: 2 phases of {ds_read | stage 1 op-half |
// barrier | setprio + 16 MFMA | barrier}, one counted vmcnt(8)/tile-end (never 0 in-loop).
// MAIN launch: grid 768 = 4m x 192 panels (N=49152, zero ragged) = exactly 3 dispatch
// rounds at 1 block/CU -> no tail quantization. Ragged cols handled by separate launch.
template <int K, int N, int EPI>
__global__ __launch_bounds__(512, 1) void gemm256k(const unsigned short* __restrict__ Ag,
                                                   const unsigned short* __restrict__ Btg,
                                                   const float* __restrict__ bias,
                                                   unsigned short* __restrict__ Cbf,
                                                   float* __restrict__ Cf,
                                                   float* __restrict__ pmax,
                                                   float* __restrict__ psum) {
  __shared__ unsigned short lds[8 * 8192];
  unsigned short* Aring = lds;
  unsigned short* Bring = lds + 4 * 8192;

  const int tid = threadIdx.x;
  const int lane = tid & 63;
  const int wid = tid >> 6;

  const int nwg = gridDim.x;  // 768: divisible by 8
  const int wgid = (blockIdx.x & 7) * (nwg >> 3) + (blockIdx.x >> 3);
  const int m0 = (wgid & 3) * 256;
  const int panel = wgid >> 2;
  const int n0 = panel * 256;

  const int r0 = (wid * 2) * 16 + (lane >> 2);
  const int r1 = r0 + 16;
  const int cg = (lane & 3) ^ ((lane >> 3) & 3);
  const unsigned short* pa0 = Ag + (size_t)(m0 + r0) * K + cg * 8;
  const unsigned short* pa1 = Ag + (size_t)(m0 + r1) * K + cg * 8;
  int rg0 = n0 + r0; rg0 = rg0 < N ? rg0 : N - 1;
  int rg1 = n0 + r1; rg1 = rg1 < N ? rg1 : N - 1;
  const unsigned short* pb0 = Btg + (size_t)rg0 * K + cg * 8;
  const unsigned short* pb1 = Btg + (size_t)rg1 * K + cg * 8;
  const int li0 = wid * 2, li1 = wid * 2 + 1;

  const int wr = wid >> 2, wc = wid & 3;
  const int l15 = lane & 15, kb = lane >> 4;
  f32x4 acc[8][4] = {};

  const int HS = K / 32;
#pragma unroll
  for (int hh = 0; hh < 3; ++hh) {
    const int ko = hh * 32, sl = hh & 3;
    gld16(pa0 + ko, &Aring[sl * 8192 + li0 * 512]);
    gld16(pa1 + ko, &Aring[sl * 8192 + li1 * 512]);
    gld16(pb0 + ko, &Bring[sl * 8192 + li0 * 512]);
    gld16(pb1 + ko, &Bring[sl * 8192 + li1 * 512]);
  }
  asm volatile("s_waitcnt vmcnt(8)" ::: "memory");
  BAR();

#pragma unroll 1
  for (int h = 0; h < HS; ++h) {
    const int slot = h & 3;
    const int nslot = (h + 3) & 3;
    const int kst = (h + 3) * 32;
    const bool st = (h + 3) < HS;
    const unsigned short* As_ = &Aring[slot * 8192];
    const unsigned short* Bs_ = &Bring[slot * 8192];

    bf16x8 afA[4], bfr[4];
#pragma unroll
    for (int i = 0; i < 4; ++i) {
      const int row = wr * 128 + i * 16 + l15;
      afA[i] = *(const bf16x8*)&As_[row * 32 + (kb ^ ((row >> 1) & 3)) * 8];
    }
#pragma unroll
    for (int j = 0; j < 4; ++j) {
      const int col = wc * 64 + j * 16 + l15;
      bfr[j] = *(const bf16x8*)&Bs_[col * 32 + (kb ^ ((col >> 1) & 3)) * 8];
    }
    if (st) {
      gld16(pa0 + kst, &Aring[nslot * 8192 + li0 * 512]);
      gld16(pa1 + kst, &Aring[nslot * 8192 + li1 * 512]);
    }
    BAR();
    __builtin_amdgcn_s_setprio(1);
#pragma unroll
    for (int i = 0; i < 4; ++i)
#pragma unroll
      for (int j = 0; j < 4; ++j)
        acc[i][j] = __builtin_amdgcn_mfma_f32_16x16x32_bf16(afA[i], bfr[j], acc[i][j], 0, 0, 0);
    __builtin_amdgcn_s_setprio(0);
    BAR();

    bf16x8 afB[4];
#pragma unroll
    for (int i = 0; i < 4; ++i) {
      const int row = wr * 128 + (i + 4) * 16 + l15;
      afB[i] = *(const bf16x8*)&As_[row * 32 + (kb ^ ((row >> 1) & 3)) * 8];
    }
    if (st) {
      gld16(pb0 + kst, &Bring[nslot * 8192 + li0 * 512]);
      gld16(pb1 + kst, &Bring[nslot * 8192 + li1 * 512]);
    }
    BAR();
    __builtin_amdgcn_s_setprio(1);
#pragma unroll
    for (int i = 0; i < 4; ++i)
#pragma unroll
      for (int j = 0; j < 4; ++j)
        acc[i + 4][j] =
            __builtin_amdgcn_mfma_f32_16x16x32_bf16(afB[i], bfr[j], acc[i + 4][j], 0, 0, 0);
    __builtin_amdgcn_s_setprio(0);

    if (h + 1 < HS) {
      if (h + 4 <= HS)
        asm volatile("s_waitcnt vmcnt(8)" ::: "memory");
      else if (h + 3 == HS)
        asm volatile("s_waitcnt vmcnt(4)" ::: "memory");
      else
        asm volatile("s_waitcnt vmcnt(0)" ::: "memory");
      BAR();
    }
  }

  float bv[4];
  bool val[4];
#pragma unroll
  for (int j = 0; j < 4; ++j) {
    const int cgl = n0 + wc * 64 + 16 * j + l15;
    val[j] = (cgl < N);
    bv[j] = bias[val[j] ? cgl : 0];
  }
#pragma unroll
  for (int i = 0; i < 8; ++i) {
    const int rbase = m0 + wr * 128 + 16 * i + 4 * kb;
#pragma unroll
    for (int j = 0; j < 4; ++j) {
      if (val[j]) {
        const int cgl = n0 + wc * 64 + 16 * j + l15;
#pragma unroll
        for (int rr = 0; rr < 4; ++rr) {
          const float v = acc[i][j][rr] + bv[j];
          if (EPI == 0)
            Cbf[(size_t)(rbase + rr) * N + cgl] = f2bf(v > 0.f ? v : 0.f);
          else
            Cf[(size_t)(rbase + rr) * N + cgl] = v;
        }
      }
    }
  }

  if constexpr (EPI == 1) {
    __syncthreads();
    float* redm = (float*)&lds[0];
    float* reds = redm + 1024;
#pragma unroll
    for (int i = 0; i < 8; ++i) {
#pragma unroll
      for (int rr = 0; rr < 4; ++rr) {
        float mx = -3.0e38f;
#pragma unroll
        for (int j = 0; j < 4; ++j)
          if (val[j]) mx = fmaxf(mx, acc[i][j][rr] + bv[j]);
#pragma unroll
        for (int d = 1; d < 16; d <<= 1) mx = fmaxf(mx, __shfl_xor(mx, d));
        float s = 0.f;
#pragma unroll
        for (int j = 0; j < 4; ++j)
          if (val[j]) s += expf(acc[i][j][rr] + bv[j] - mx);
#pragma unroll
        for (int d = 1; d < 16; d <<= 1) s += __shfl_xor(s, d);
        if (l15 == 0) {
          const int rw = wr * 128 + 16 * i + 4 * kb + rr;
          redm[wc * 256 + rw] = mx;
          reds[wc * 256 + rw] = s;
        }
      }
    }
    __syncthreads();
    if (tid < 256) {
      float mm = redm[tid], ss = reds[tid];
#pragma unroll
      for (int w = 1; w < 4; ++w) {
        const float ma = redm[w * 256 + tid], sa = reds[w * 256 + tid];
        const float nm = fmaxf(mm, ma);
        ss = ss * expf(mm - nm) + sa * expf(ma - nm);
        mm = nm;
      }
      pmax[(size_t)(m0 + tid) * PSTRIDE + panel] = mm;
      psum[(size_t)(m0 + tid) * PSTRIDE + panel] = ss;
    }
  }
}

// ---- RAGGED-TAIL 128x256 kernel (R8-proven): panels PBASE.., half-duration blocks ----
template <int K, int N, int EPI, int PBASE>
__global__ __launch_bounds__(512, 1) void gemm128x256(const unsigned short* __restrict__ Ag,
                                                      const unsigned short* __restrict__ Btg,
                                                      const float* __restrict__ bias,
                                                      unsigned short* __restrict__ Cbf,
                                                      float* __restrict__ Cf,
                                                      float* __restrict__ pmax,
                                                      float* __restrict__ psum) {
  __shared__ unsigned short lds[4 * 4096 + 4 * 8192];
  unsigned short* Aring = lds;
  unsigned short* Bring = lds + 4 * 4096;

  const int tid = threadIdx.x;
  const int lane = tid & 63;
  const int wid = tid >> 6;

  const int nwg = gridDim.x;
  const int wgid = (blockIdx.x & 7) * (nwg >> 3) + (blockIdx.x >> 3);
  const int m0 = (wgid & 7) * 128;
  const int panel = wgid >> 3;
  const int n0 = (PBASE + panel) * 256;

  const int cg = (lane & 3) ^ ((lane >> 3) & 3);
  const int arow = wid * 16 + (lane >> 2);
  const unsigned short* pa = Ag + (size_t)(m0 + arow) * K + cg * 8;
  const int br0 = wid * 32 + (lane >> 2), br1 = br0 + 16;
  int rg0 = n0 + br0; rg0 = rg0 < N ? rg0 : N - 1;
  int rg1 = n0 + br1; rg1 = rg1 < N ? rg1 : N - 1;
  const unsigned short* pb0 = Btg + (size_t)rg0 * K + cg * 8;
  const unsigned short* pb1 = Btg + (size_t)rg1 * K + cg * 8;
  const int li0 = wid * 2, li1 = wid * 2 + 1;

  const int wr = wid >> 2, wc = wid & 3;
  const int l15 = lane & 15, kb = lane >> 4;
  f32x4 acc[4][4] = {};

  const int HS = K / 32;
#pragma unroll
  for (int hh = 0; hh < 3; ++hh) {
    const int ko = hh * 32;
    gld16(pa + ko, &Aring[hh * 4096 + wid * 512]);
    gld16(pb0 + ko, &Bring[hh * 8192 + li0 * 512]);
    gld16(pb1 + ko, &Bring[hh * 8192 + li1 * 512]);
  }
  asm volatile("s_waitcnt vmcnt(6)" ::: "memory");
  BAR();

#pragma unroll 1
  for (int h = 0; h < HS; ++h) {
    const int slot = h & 3;
    const int nslot = (h + 3) & 3;
    const int kst = (h + 3) * 32;
    const unsigned short* As_ = &Aring[slot * 4096];
    const unsigned short* Bs_ = &Bring[slot * 8192];

    if (h + 3 < HS) {
      gld16(pa + kst, &Aring[nslot * 4096 + wid * 512]);
      gld16(pb0 + kst, &Bring[nslot * 8192 + li0 * 512]);
      gld16(pb1 + kst, &Bring[nslot * 8192 + li1 * 512]);
    }

    bf16x8 af[4], bf[4];
#pragma unroll
    for (int i = 0; i < 4; ++i) {
      const int row = wr * 64 + i * 16 + l15;
      af[i] = *(const bf16x8*)&As_[row * 32 + (kb ^ ((row >> 1) & 3)) * 8];
    }
#pragma unroll
    for (int j = 0; j < 4; ++j) {
      const int col = wc * 64 + j * 16 + l15;
      bf[j] = *(const bf16x8*)&Bs_[col * 32 + (kb ^ ((col >> 1) & 3)) * 8];
    }
    __builtin_amdgcn_s_setprio(1);
#pragma unroll
    for (int i = 0; i < 4; ++i)
#pragma unroll
      for (int j = 0; j < 4; ++j)
        acc[i][j] = __builtin_amdgcn_mfma_f32_16x16x32_bf16(af[i], bf[j], acc[i][j], 0, 0, 0);
    __builtin_amdgcn_s_setprio(0);

    if (h + 1 < HS) {
      if (h + 4 <= HS)
        asm volatile("s_waitcnt vmcnt(6)" ::: "memory");
      else if (h + 3 == HS)
        asm volatile("s_waitcnt vmcnt(3)" ::: "memory");
      else
        asm volatile("s_waitcnt vmcnt(0)" ::: "memory");
      BAR();
    }
  }

  float bv[4];
  bool val[4];
#pragma unroll
  for (int j = 0; j < 4; ++j) {
    const int cgl = n0 + wc * 64 + 16 * j + l15;
    val[j] = (cgl < N);
    bv[j] = bias[val[j] ? cgl : 0];
  }
#pragma unroll
  for (int i = 0; i < 4; ++i) {
    const int rbase = m0 + wr * 64 + 16 * i + 4 * kb;
#pragma unroll
    for (int j = 0; j < 4; ++j) {
      if (val[j]) {
        const int cgl = n0 + wc * 64 + 16 * j + l15;
#pragma unroll
        for (int rr = 0; rr < 4; ++rr) {
          const float v = acc[i][j][rr] + bv[j];
          if (EPI == 0)
            Cbf[(size_t)(rbase + rr) * N + cgl] = f2bf(v > 0.f ? v : 0.f);
          else
            Cf[(size_t)(rbase + rr) * N + cgl] = v;
        }
      }
    }
  }

  if constexpr (EPI == 1) {
    __syncthreads();
    float* redm = (float*)&lds[0];
    float* reds = redm + 512;
#pragma unroll
    for (int i = 0; i < 4; ++i) {
#pragma unroll
      for (int rr = 0; rr < 4; ++rr) {
        float mx = -3.0e38f;
#pragma unroll
        for (int j = 0; j < 4; ++j)
          if (val[j]) mx = fmaxf(mx, acc[i][j][rr] + bv[j]);
#pragma unroll
        for (int d = 1; d < 16; d <<= 1) mx = fmaxf(mx, __shfl_xor(mx, d));
        float s = 0.f;
#pragma unroll
        for (int j = 0; j < 4; ++j)
          if (val[j]) s += expf(acc[i][j][rr] + bv[j] - mx);
#pragma unroll
        for (int d = 1; d < 16; d <<= 1) s += __shfl_xor(s, d);
        if (l15 == 0) {
          const int rw = wr * 64 + 16 * i + 4 * kb + rr;
          redm[wc * 128 + rw] = mx;
          reds[wc * 128 + rw] = s;
        }
      }
    }
    __syncthreads();
    if (tid < 128) {
      float mm = redm[tid], ss = reds[tid];
#pragma unroll
      for (int w = 1; w < 4; ++w) {
        const float ma = redm[w * 128 + tid], sa = reds[w * 128 + tid];
        const float nm = fmaxf(mm, ma);
        ss = ss * expf(mm - nm) + sa * expf(ma - nm);
        mm = nm;
      }
      pmax[(size_t)(m0 + tid) * PSTRIDE + PBASE + panel] = mm;
      psum[(size_t)(m0 + tid) * PSTRIDE + PBASE + panel] = ss;
    }
  }
}

// ---------------- m97-structure 128x128 GEMM (GEMM1) ----------------
template <int K, int N, int EPI>
__global__ __launch_bounds__(256, 2) void gemm128(const unsigned short* __restrict__ Ag,
                                                  const unsigned short* __restrict__ Btg,
                                                  const float* __restrict__ bias,
                                                  unsigned short* __restrict__ Cbf,
                                                  float* __restrict__ Cf) {
  __shared__ unsigned short As[2][128 * 64];
  __shared__ unsigned short Bs[2][128 * 64];
  const int tid = threadIdx.x;
  const int lane = tid & 63;
  const int wid = tid >> 6;
  const int nwg = gridDim.x;
  const int wgid = (blockIdx.x & 7) * (nwg >> 3) + (blockIdx.x >> 3);
  const int m0 = (wgid & 7) * 128;
  const int n0 = (wgid >> 3) * 128;
  const int srsub = lane >> 3;
  const int scg = (lane & 7) ^ srsub;
  const unsigned short* pa[4];
  const unsigned short* pb[4];
#pragma unroll
  for (int qq = 0; qq < 4; ++qq) {
    const int seg = wid * 4 + qq;
    const int row = seg * 8 + srsub;
    pa[qq] = Ag + (size_t)(m0 + row) * K + scg * 8;
    int rg = n0 + row;
    rg = rg < N ? rg : N - 1;
    pb[qq] = Btg + (size_t)rg * K + scg * 8;
  }
  auto stage = [&](int t, int s) {
    const int ko = t * 64;
#pragma unroll
    for (int qq = 0; qq < 4; ++qq) {
      const int seg = wid * 4 + qq;
      gld16(pa[qq] + ko, &As[s][seg * 512]);
      gld16(pb[qq] + ko, &Bs[s][seg * 512]);
    }
  };
  const int wr = wid >> 1, wc = wid & 1;
  const int l15 = lane & 15, kb = lane >> 4;
  f32x4 acc[4][4] = {};
  auto compute = [&](int s) {
#pragma unroll
    for (int koi = 0; koi < 2; ++koi) {
      bf16x8 af[4], bf[4];
#pragma unroll
      for (int i = 0; i < 4; ++i) {
        const int row = wr * 64 + i * 16 + l15;
        af[i] = *(const bf16x8*)&As[s][row * 64 + ((koi * 4 + kb) ^ (row & 7)) * 8];
      }
#pragma unroll
      for (int j = 0; j < 4; ++j) {
        const int col = wc * 64 + j * 16 + l15;
        bf[j] = *(const bf16x8*)&Bs[s][col * 64 + ((koi * 4 + kb) ^ (col & 7)) * 8];
      }
#pragma unroll
      for (int i = 0; i < 4; ++i)
#pragma unroll
        for (int j = 0; j < 4; ++j)
          acc[i][j] = __builtin_amdgcn_mfma_f32_16x16x32_bf16(af[i], bf[j], acc[i][j], 0, 0, 0);
    }
  };
  const int NT = K / 64;
  stage(0, 0);
  asm volatile("s_waitcnt vmcnt(0)" ::: "memory");
  __syncthreads();
#pragma unroll 1
  for (int t = 0; t < NT; ++t) {
    if (t + 1 < NT) stage(t + 1, (t + 1) & 1);
    compute(t & 1);
    asm volatile("s_waitcnt vmcnt(0)" ::: "memory");
    __syncthreads();
  }
  float bv[4];
  bool val[4];
#pragma unroll
  for (int j = 0; j < 4; ++j) {
    const int cg2 = n0 + wc * 64 + 16 * j + l15;
    val[j] = (cg2 < N);
    bv[j] = bias[val[j] ? cg2 : 0];
  }
#pragma unroll
  for (int i = 0; i < 4; ++i) {
    const int rbase = m0 + wr * 64 + 16 * i + 4 * kb;
#pragma unroll
    for (int j = 0; j < 4; ++j) {
      if (val[j]) {
        const int cg2 = n0 + wc * 64 + 16 * j + l15;
#pragma unroll
        for (int rr = 0; rr < 4; ++rr) {
          const float v = acc[i][j][rr] + bv[j];
          if (EPI == 0)
            Cbf[(size_t)(rbase + rr) * N + cg2] = f2bf(v > 0.f ? v : 0.f);
          else
            Cf[(size_t)(rbase + rr) * N + cg2] = v;
        }
      }
    }
  }
}

// ======== fallback (round-2) GEMM, used when ws is too small for the bf16 W copies ========
template <int K, int N, int EPI>
__global__ __launch_bounds__(512, 2) void gemm_fused(const unsigned short* __restrict__ Ag,
                                                     const float* __restrict__ Bg,
                                                     const float* __restrict__ bias,
                                                     unsigned short* __restrict__ Cbf,
                                                     float* __restrict__ Cf,
                                                     float* __restrict__ pmax,
                                                     float* __restrict__ psum) {
  __shared__ unsigned short As[2][256 * 64];
  __shared__ uint4 Bs[2][8 * 128];
  const int tid = threadIdx.x;
  const int lane = tid & 63;
  const int wid = tid >> 6;
  const int m0 = blockIdx.x * 256;
  const int n0 = blockIdx.y * 128;
  const int arow = tid >> 3;
  const int ach = tid & 7;
  const int bn = 2 * lane;
  const int bk = 8 * wid;
  const int bcolg = (n0 + bn < N - 2) ? (n0 + bn) : (N - 2);
  uint4 areg[4];
  float2 breg[8];
  f32x4 acc[4][4] = {};
  auto stage_global = [&](int kt) {
    const int k0 = kt * 64;
#pragma unroll
    for (int qq = 0; qq < 4; ++qq)
      areg[qq] = *(const uint4*)&Ag[(size_t)(m0 + arow + 64 * qq) * K + k0 + 8 * ach];
#pragma unroll
    for (int i = 0; i < 8; ++i) breg[i] = *(const float2*)&Bg[(size_t)(k0 + bk + i) * N + bcolg];
  };
  auto stage_lds = [&](int buf) {
#pragma unroll
    for (int qq = 0; qq < 4; ++qq) {
      const int row = arow + 64 * qq;
      *(uint4*)&As[buf][row * 64 + ((8 * ach) ^ ((row & 7) * 8))] = areg[qq];
    }
    uint4 c0, c1;
    c0.x = pack2(breg[0].x, breg[1].x); c0.y = pack2(breg[2].x, breg[3].x);
    c0.z = pack2(breg[4].x, breg[5].x); c0.w = pack2(breg[6].x, breg[7].x);
    c1.x = pack2(breg[0].y, breg[1].y); c1.y = pack2(breg[2].y, breg[3].y);
    c1.z = pack2(breg[4].y, breg[5].y); c1.w = pack2(breg[6].y, breg[7].y);
    Bs[buf][wid * 128 + bn] = c0;
    Bs[buf][wid * 128 + bn + 1] = c1;
  };
  const int wr = wid & 3, wc = wid >> 2;
  const int mw = 64 * wr, nw = 64 * wc;
  const int l15 = lane & 15, kb = lane >> 4;
  auto compute = [&](int buf) {
#pragma unroll
    for (int koi = 0; koi < 2; ++koi) {
      bf16x8 af[4], bfv[4];
#pragma unroll
      for (int i = 0; i < 4; ++i) {
        const int row = mw + 16 * i + l15;
        af[i] = *(const bf16x8*)&As[buf][row * 64 + ((32 * koi + 8 * kb) ^ ((row & 7) * 8))];
      }
#pragma unroll
      for (int j = 0; j < 4; ++j)
        bfv[j] = *(const bf16x8*)&Bs[buf][(4 * koi + kb) * 128 + nw + 16 * j + l15];
#pragma unroll
      for (int i = 0; i < 4; ++i)
#pragma unroll
        for (int j = 0; j < 4; ++j)
          acc[i][j] = __builtin_amdgcn_mfma_f32_16x16x32_bf16(af[i], bfv[j], acc[i][j], 0, 0, 0);
    }
  };
  const int NT = K / 64;
  stage_global(0);
  stage_lds(0);
  __syncthreads();
  for (int t = 0; t < NT; ++t) {
    const int cur = t & 1;
    if (t + 1 < NT) stage_global(t + 1);
    compute(cur);
    if (t + 1 < NT) stage_lds(cur ^ 1);
    __syncthreads();
  }
  float bv[4];
  bool val[4];
#pragma unroll
  for (int j = 0; j < 4; ++j) {
    const int cg2 = n0 + nw + 16 * j + l15;
    val[j] = (cg2 < N);
    bv[j] = bias[val[j] ? cg2 : 0];
  }
#pragma unroll
  for (int i = 0; i < 4; ++i) {
    const int rbase = m0 + mw + 16 * i + 4 * kb;
#pragma unroll
    for (int j = 0; j < 4; ++j) {
      if (val[j]) {
        const int cg2 = n0 + nw + 16 * j + l15;
#pragma unroll
        for (int rr = 0; rr < 4; ++rr) {
          const float v = acc[i][j][rr] + bv[j];
          if (EPI == 0)
            Cbf[(size_t)(rbase + rr) * N + cg2] = f2bf(v > 0.f ? v : 0.f);
          else
            Cf[(size_t)(rbase + rr) * N + cg2] = v;
        }
      }
    }
  }
  if constexpr (EPI == 1) {
    float* redm = (float*)&As[0][0];
    float* reds = redm + 512;
#pragma unroll
    for (int i = 0; i < 4; ++i) {
#pragma unroll
      for (int rr = 0; rr < 4; ++rr) {
        float mx = -3.0e38f;
#pragma unroll
        for (int j = 0; j < 4; ++j)
          if (val[j]) mx = fmaxf(mx, acc[i][j][rr] + bv[j]);
#pragma unroll
        for (int d = 1; d < 16; d <<= 1) mx = fmaxf(mx, __shfl_xor(mx, d));
        float s = 0.f;
#pragma unroll
        for (int j = 0; j < 4; ++j)
          if (val[j]) s += expf(acc[i][j][rr] + bv[j] - mx);
#pragma unroll
        for (int d = 1; d < 16; d <<= 1) s += __shfl_xor(s, d);
        if (l15 == 0) {
          const int rl = mw + 16 * i + 4 * kb + rr;
          redm[wc * 256 + rl] = mx;
          reds[wc * 256 + rl] = s;
        }
      }
    }
    __syncthreads();
    if (tid < 256) {
      const float ma = redm[tid], mb = redm[256 + tid];
      const float mm = fmaxf(ma, mb);
      const float ss = reds[tid] * expf(ma - mm) + reds[256 + tid] * expf(mb - mm);
      pmax[(size_t)(m0 + tid) * PSTRIDE + blockIdx.y] = mm;
      psum[(size_t)(m0 + tid) * PSTRIDE + blockIdx.y] = ss;
    }
  }
}

// ---------------- reduce per-block partials -> row max & sumexp ----------------
__global__ void smax1r(const float* __restrict__ pmax, const float* __restrict__ psum,
                       float* __restrict__ rms, int ntiles) {
  const int b = blockIdx.x;
  const int l = threadIdx.x;
  float m = -3.4e38f, s = 0.f;
  for (int i = l; i < ntiles; i += 64) {
    const float pm = pmax[(size_t)b * PSTRIDE + i];
    const float ps = psum[(size_t)b * PSTRIDE + i];
    const float nm = fmaxf(m, pm);
    s = s * expf(m - nm) + ps * expf(pm - nm);
    m = nm;
  }
  for (int d = 1; d < 64; d <<= 1) {
    const float om = __shfl_xor(m, d), os = __shfl_xor(s, d);
    const float nm = fmaxf(m, om);
    s = s * expf(m - nm) + os * expf(om - nm);
    m = nm;
  }
  if (l == 0) {
    rms[b] = m;
    rms[B_DIM + b] = s;
  }
}

// ---------------- softmax pass 2: probs in-place + log_softmax(probs) at label ----------------
__global__ void smax2(float* __restrict__ buf, const float* __restrict__ rms,
                      const int* __restrict__ labels, float* __restrict__ row_lp) {
  const int b = blockIdx.x;
  float4* p = (float4*)(buf + (size_t)b * NITEM);
  const float m = rms[b];
  const float inv = 1.f / rms[B_DIM + b];  // = max(probs)
  const int lab = labels[b];
  __shared__ float s_pl;
  __shared__ float ss[256];
  float s2 = 0.f;
  for (int i = threadIdx.x; i < NITEM / 4; i += 256) {
    const float4 v = p[i];
    float pr[4];
#pragma unroll
    for (int j = 0; j < 4; ++j) {
      pr[j] = expf((&v.x)[j] - m) * inv;
      s2 += expf(pr[j] - inv);
    }
    float4 w;
    w.x = pr[0]; w.y = pr[1]; w.z = pr[2]; w.w = pr[3];
    p[i] = w;
    if ((lab >> 2) == i) s_pl = pr[lab & 3];
  }
  ss[threadIdx.x] = s2;
  __syncthreads();
  for (int off = 128; off > 0; off >>= 1) {
    if (threadIdx.x < off) ss[threadIdx.x] += ss[threadIdx.x + off];
    __syncthreads();
  }
  if (threadIdx.x == 0) row_lp[b] = s_pl - (inv + logf(ss[0]));
}

// ---------------- finalize: labels (as float) + loss ----------------
__global__ void fin(const float* __restrict__ row_lp, const int* __restrict__ labels,
                    float* __restrict__ out) {
  __shared__ float sb[256];
  float a = 0.f;
  for (int i = threadIdx.x; i < B_DIM; i += 256) {
    a += row_lp[i];
    out[(size_t)B_DIM * NITEM + i] = (float)labels[i];
  }
  sb[threadIdx.x] = a;
  __syncthreads();
  for (int off = 128; off > 0; off >>= 1) {
    if (threadIdx.x < off) sb[threadIdx.x] += sb[threadIdx.x + off];
    __syncthreads();
  }
  if (threadIdx.x == 0) out[(size_t)B_DIM * NITEM + B_DIM] = -sb[0] / (float)B_DIM;
}

extern "C" void kernel_launch(void* const* d_in, const int* in_sizes, int n_in,
                              void* d_out, int out_size, void* d_ws, size_t ws_size,
                              hipStream_t stream) {
  const int* item_ids = (const int*)d_in[0];
  const int* item_len = (const int*)d_in[1];
  const int* ent_ids = (const int*)d_in[2];
  const int* ent_len = (const int*)d_in[3];
  const int* word_ids = (const int*)d_in[4];
  const int* word_len = (const int*)d_in[5];
  const int* labels = (const int*)d_in[6];
  const float* item_emb = (const float*)d_in[7];
  const float* ent_emb = (const float*)d_in[8];
  const float* word_emb = (const float*)d_in[9];
  const float* W1 = (const float*)d_in[10];
  const float* b1 = (const float*)d_in[11];
  const float* W2 = (const float*)d_in[12];
  const float* b2 = (const float*)d_in[13];

  float* out = (float*)d_out;
  char* ws = (char*)d_ws;
  unsigned short* u_bf = (unsigned short*)ws;                 // 1 MB   [1024][512] bf16
  unsigned short* h_bf = (unsigned short*)(ws + (1 << 20));   // 4 MB   [1024][2048] bf16
  float* pmax = (float*)(ws + 5 * (1 << 20));                 // 1.6 MB [1024][400]
  float* psum = (float*)(ws + 7 * (1 << 20));                 // 1.6 MB
  float* rms = (float*)(ws + 9 * (1 << 20));                  // [2][1024]
  float* row_lp = rms + 2 * B_DIM;
  unsigned short* W1t = (unsigned short*)(ws + 10 * (1 << 20));  // 2 MB [2048][512] bf16
  unsigned short* W2t = (unsigned short*)(ws + 16 * (1 << 20));  // 204.8 MB [50000][2048] bf16
  float* logits = out;

  const size_t need = (size_t)16 * (1 << 20) + (size_t)NITEM * 2048 * 2;
  const bool fast = ws_size >= need;

  if (fast) {
    prep_kernel<<<2048 + 25024 + 256, 256, 0, stream>>>(item_ids, item_len, ent_ids, ent_len,
                                                        word_ids, word_len, item_emb, ent_emb,
                                                        word_emb, u_bf, W1, W1t, W2, W2t);
    gemm128<512, 2048, 0><<<8 * 16, 256, 0, stream>>>(u_bf, W1t, b1, h_bf, nullptr);
    // main: 768 blocks = 4m x 192 panels (N=49152) = exactly 3 dispatch rounds
    gemm256k<2048, NITEM, 1><<<768, 512, 0, stream>>>(h_bf, W2t, b2, nullptr, logits, pmax,
                                                      psum);
    // ragged tail: 32 half-duration blocks = 8m x 4 panels (cols 49152..50175, masked)
    gemm128x256<2048, NITEM, 1, 192><<<32, 512, 0, stream>>>(h_bf, W2t, b2, nullptr, logits,
                                                             pmax, psum);
    smax1r<<<B_DIM, 64, 0, stream>>>(pmax, psum, rms, 196);
  } else {
    mean_kernel<<<2 * B_DIM, 256, 0, stream>>>(item_ids, item_len, ent_ids, ent_len, word_ids,
                                               word_len, item_emb, ent_emb, word_emb, u_bf);
    gemm_fused<512, 2048, 0><<<dim3(4, 16), 512, 0, stream>>>(u_bf, W1, b1, h_bf, nullptr,
                                                              nullptr, nullptr);
    gemm_fused<2048, NITEM, 1><<<dim3(4, 391), 512, 0, stream>>>(h_bf, W2, b2, nullptr, logits,
                                                                 pmax, psum);
    smax1r<<<B_DIM, 64, 0, stream>>>(pmax, psum, rms, 391);
  }
  smax2<<<B_DIM, 256, 0, stream>>>(logits, rms, labels, row_lp);
  fin<<<1, 256, 0, stream>>>(row_lp, labels, out);
}